// Round 14
// baseline (89.824 us; speedup 1.0000x reference)
//
#include <hip/hip_runtime.h>
#include <hip/hip_bf16.h>

// MultiLinear: y[b,g,o] = sum_i x[b,g,i] * W[g,o,i] + bias[g,o]
// B=4096, G=16, DIN=512, DOUT=512, fp32 in/out.
// R14 = R13 (swizzled conflict-free LDS, B-DMA, hybrid staging) restructured
// into the m201 4-phase/K-tile schedule (T3+T4+T5), now that T2 is in place:
//   each phase: {ds_read frag quadrant || one staging op} -> lgkmcnt(0) ->
//   barrier -> setprio(1) 16xMFMA setprio(0) -> barrier.
//   P0: A-loads(kt+1) issue   P1: DMA_B(kt+1)   P2: cvt+ds_write A(kt+1)
//   P3: vmcnt(0) (drains only DMA_B issued 2 phases ago - already landed).
// Staging work per phase is light; loads span phases counted (T4); setprio
// has wave role-diversity to arbitrate (T5).

#define BATCH 4096
#define NGRP  16
#define DIN   512
#define DOUT  512

#define BM 256
#define BN 256
#define BK 64
#define NT (DIN / BK)   // 8 K-tiles

typedef __bf16 bf16x8 __attribute__((ext_vector_type(8)));
typedef float  f32x4  __attribute__((ext_vector_type(4)));
typedef const __attribute__((address_space(1))) void gas_void;
typedef __attribute__((address_space(3))) void las_void;

// ---------- prepass: W fp32 -> bf16 into d_ws ----------
__global__ __launch_bounds__(256)
void wcvt_kernel(const float* __restrict__ W, __bf16* __restrict__ Wb) {
    const int i = (blockIdx.x * 256 + threadIdx.x) * 8;
    f32x4 a = *(const f32x4*)(W + i);
    f32x4 b = *(const f32x4*)(W + i + 4);
    bf16x8 v;
#pragma unroll
    for (int j = 0; j < 4; ++j) { v[j] = (__bf16)a[j]; v[j + 4] = (__bf16)b[j]; }
    *(bf16x8*)(Wb + i) = v;
}

// ---------- main GEMM ----------
__global__ __launch_bounds__(512, 2)
void MultiLinear_48498770706571_kernel(const float* __restrict__ X,
                                       const __bf16* __restrict__ Wb,
                                       const float* __restrict__ Bias,
                                       float* __restrict__ Y) {
    // 512 blocks / 8 XCDs = 64 consecutive tiles (2 full groups) per XCD.
    const int bid = (blockIdx.x & 7) * 64 + (blockIdx.x >> 3);
    const int g   = bid >> 5;          // 32 tiles per group (16 m x 2 n)
    const int mt  = (bid >> 1) & 15;
    const int nt  = bid & 1;
    const int bm0 = mt * BM;
    const int bn0 = nt * BN;

    __shared__ __bf16 As[2][BM * BK];    // 64 KB: linear 128B rows, chunk-swz
    __shared__ __bf16 BsF[2][BN * BK];   // 64 KB: linear, DMA-filled, chunk-swz

    const int tid  = threadIdx.x;
    const int lane = tid & 63;
    const int w    = tid >> 6;        // 0..7
    const int wm   = (w >> 2) * 128;  // {0,128}
    const int wn   = (w & 3) * 64;    // {0,64,128,192}
    const int l15  = lane & 15;
    const int q    = lane >> 4;       // 0..3

    // A staging: 128 rows/pass (4 thr/row, 16 floats each), 2 passes.
    const int srow = tid >> 2;        // 0..127
    const int sc2  = (tid & 3) * 2;   // first 16B-chunk (of 8) this thr writes
    const float* pA = X + (size_t)(bm0 + srow) * (NGRP * DIN) + g * DIN + (tid & 3) * 16;
    const size_t strideA = (size_t)128 * (NGRP * DIN);

    // B DMA geometry: per wave 32 rows; 4 issues of 1 KB (8 rows x 128 B).
    const int drow0 = (w << 5) + (lane >> 3);
    const int dch   = lane & 7;
    const __bf16* wbase = Wb + (size_t)g * (DOUT * DIN) + (size_t)bn0 * DIN;

    f32x4 ra[2][4];   // 32 VGPRs in flight (A only; B is DMA)

#define ISSUE_A(k0)                                                        \
    do {                                                                   \
        const f32x4* qa0 = (const f32x4*)(pA + (k0));                      \
        const f32x4* qa1 = (const f32x4*)(pA + strideA + (k0));            \
        ra[0][0] = qa0[0]; ra[0][1] = qa0[1]; ra[0][2] = qa0[2]; ra[0][3] = qa0[3]; \
        ra[1][0] = qa1[0]; ra[1][1] = qa1[1]; ra[1][2] = qa1[2]; ra[1][3] = qa1[3]; \
    } while (0)

#define CVT_WRITE_A(buf)                                                   \
    do {                                                                   \
        _Pragma("unroll")                                                  \
        for (int p = 0; p < 2; ++p) {                                      \
            bf16x8 v0, v1;                                                 \
            _Pragma("unroll")                                              \
            for (int j = 0; j < 4; ++j) {                                  \
                v0[j] = (__bf16)ra[p][0][j]; v0[j + 4] = (__bf16)ra[p][1][j]; \
                v1[j] = (__bf16)ra[p][2][j]; v1[j + 4] = (__bf16)ra[p][3][j]; \
            }                                                              \
            const int row = p * 128 + srow;                                \
            const int s   = srow & 7;                                      \
            __bf16* base = &As[buf][row * BK];                             \
            *(bf16x8*)&base[((sc2 ^ s) << 3)]       = v0;                  \
            *(bf16x8*)&base[(((sc2 + 1) ^ s) << 3)] = v1;                  \
        }                                                                  \
    } while (0)

#define DMA_B(kt, buf)                                                     \
    do {                                                                   \
        const size_t k0 = (size_t)(kt) * BK;                               \
        _Pragma("unroll")                                                  \
        for (int qq = 0; qq < 4; ++qq) {                                   \
            const int row = drow0 + (qq << 3);                             \
            const __bf16* gp = wbase + (size_t)row * DIN + k0              \
                               + ((dch ^ (row & 7)) << 3);                 \
            __builtin_amdgcn_global_load_lds(                              \
                (gas_void*)gp,                                             \
                (las_void*)&BsF[buf][(w << 11) + (qq << 9)], 16, 0, 0);    \
        }                                                                  \
    } while (0)

#define READ_AF(MLO, KK, buf)                                              \
    do {                                                                   \
        _Pragma("unroll")                                                  \
        for (int mi = 0; mi < 4; ++mi) {                                   \
            const int row = wm + ((MLO) + mi) * 16 + l15;                  \
            const int ch  = (((KK) << 2) + q) ^ (row & 7);                 \
            af[mi] = *(const bf16x8*)&As[buf][row * BK + (ch << 3)];       \
        }                                                                  \
    } while (0)

#define READ_BF(KK, buf)                                                   \
    do {                                                                   \
        _Pragma("unroll")                                                  \
        for (int ni = 0; ni < 4; ++ni) {                                   \
            const int brow = wn + ni * 16 + l15;                           \
            const int ch   = (((KK) << 2) + q) ^ (brow & 7);               \
            bfr[ni] = *(const bf16x8*)&BsF[buf][brow * BK + (ch << 3)];    \
        }                                                                  \
    } while (0)

#define MFMA_Q(MLO)                                                        \
    do {                                                                   \
        __builtin_amdgcn_s_setprio(1);                                     \
        _Pragma("unroll")                                                  \
        for (int mi = 0; mi < 4; ++mi)                                     \
            _Pragma("unroll")                                              \
            for (int ni = 0; ni < 4; ++ni)                                 \
                acc[(MLO) + mi][ni] = __builtin_amdgcn_mfma_f32_16x16x32_bf16( \
                    af[mi], bfr[ni], acc[(MLO) + mi][ni], 0, 0, 0);        \
        __builtin_amdgcn_s_setprio(0);                                     \
    } while (0)

#define LGKM0() asm volatile("s_waitcnt lgkmcnt(0)" ::: "memory")
#define BAR()   __builtin_amdgcn_s_barrier()

    f32x4 acc[8][4];
#pragma unroll
    for (int mi = 0; mi < 8; ++mi)
#pragma unroll
        for (int ni = 0; ni < 4; ++ni) acc[mi][ni] = f32x4{0.f, 0.f, 0.f, 0.f};

    // prologue: stage tile 0 into buf 0
    ISSUE_A(0);
    DMA_B(0, 0);
    CVT_WRITE_A(0);                                  // waits ra(0)
    asm volatile("s_waitcnt vmcnt(0)" ::: "memory"); // drain DMA_B(0)
    LGKM0();
    BAR();

    for (int kt = 0; kt < NT; ++kt) {
        const int cur = kt & 1;
        const int nxt = cur ^ 1;
        const bool pre = (kt + 1 < NT);
        bf16x8 af[4], bfr[4];

        // ---- P0: frags (m0-3, kk0) + B(kk0); issue A(kt+1) loads ----
        READ_AF(0, 0, cur);
        READ_BF(0, cur);
        if (pre) ISSUE_A((kt + 1) * BK);
        LGKM0(); BAR();
        MFMA_Q(0);
        BAR();

        // ---- P1: frags (m4-7, kk0); DMA B(kt+1) ----
        READ_AF(4, 0, cur);
        if (pre) DMA_B(kt + 1, nxt);
        LGKM0(); BAR();
        MFMA_Q(4);
        BAR();

        // ---- P2: frags (m0-3, kk1) + B(kk1); cvt+write A(kt+1) ----
        READ_AF(0, 1, cur);
        READ_BF(1, cur);
        if (pre) CVT_WRITE_A(nxt);   // ra landed (issued 2 phases ago)
        LGKM0(); BAR();
        MFMA_Q(0);
        BAR();

        // ---- P3: frags (m4-7, kk1); drain DMA_B(kt+1) before close ----
        READ_AF(4, 1, cur);
        LGKM0();
        if (pre) asm volatile("s_waitcnt vmcnt(0)" ::: "memory");
        BAR();
        MFMA_Q(4);
        BAR();
    }

    // epilogue: C/D layout col = lane&15, row = (lane>>4)*4 + j (verified R1)
    const int r0 = (lane >> 4) * 4;
    const int c  = lane & 15;
    float bias_n[4];
#pragma unroll
    for (int ni = 0; ni < 4; ++ni)
        bias_n[ni] = Bias[g * DOUT + bn0 + wn + ni * 16 + c];
#pragma unroll
    for (int mi = 0; mi < 8; ++mi) {
#pragma unroll
        for (int j = 0; j < 4; ++j) {
            const int row = bm0 + wm + mi * 16 + r0 + j;
            float* yrow = Y + (size_t)row * (NGRP * DOUT) + g * DOUT + bn0 + wn;
#pragma unroll
            for (int ni = 0; ni < 4; ++ni)
                yrow[ni * 16 + c] = acc[mi][ni][j] + bias_n[ni];
        }
    }
#undef ISSUE_A
#undef CVT_WRITE_A
#undef DMA_B
#undef READ_AF
#undef READ_BF
#undef MFMA_Q
#undef LGKM0
#undef BAR
}

extern "C" void kernel_launch(void* const* d_in, const int* in_sizes, int n_in,
                              void* d_out, int out_size, void* d_ws, size_t ws_size,
                              hipStream_t stream) {
    const float* X    = (const float*)d_in[0];
    const float* W    = (const float*)d_in[1];
    const float* Bias = (const float*)d_in[2];
    float* Y          = (float*)d_out;
    __bf16* Wb        = (__bf16*)d_ws;   // 8 MB scratch

    // prepass: 16*512*512 = 4M elems / (256 thr * 8 elems) = 2048 blocks
    wcvt_kernel<<<2048, 256, 0, stream>>>(W, Wb);

    const int grid = NGRP * (BATCH / BM) * (DOUT / BN);  // 512
    MultiLinear_48498770706571_kernel<<<grid, 512, 0, stream>>>(X, Wb, Bias, Y);
}

// Round 15
// 72.640 us; speedup vs baseline: 1.2366x; 1.2366x over previous
//
#include <hip/hip_runtime.h>
#include <hip/hip_bf16.h>

// MultiLinear: y[b,g,o] = sum_i x[b,g,i] * W[g,o,i] + bias[g,o]
// B=4096, G=16, DIN=512, DOUT=512, fp32 in/out.
// R15: X READ ONCE. Cross-round data shows dur tracks fp32-X read volume
// (BN=256 -> 256MB -> 84-93us; BN=128 -> 512MB -> 112-121us), not schedule.
// So BN=512 (full DOUT): X re-read factor 2 -> 1. BM=128, BK=64, 8 waves,
// wave-tile 128x64 (wm=0 all waves, acc=128 AGPR). LDS = 32KB A + 128KB B
// = 160KB exactly (1 block/CU). W per group = 512KB bf16 -> per-XCD 1MB,
// L2-resident despite 32x re-read. Everything else is the R9/R13 verified
// machinery: A reg-staged fp32->bf16 dist-1, B bf16-DMA (W-prepass),
// conflict-free chunk-XOR swizzle both sides (R13: 0 conflicts), counted
// vmcnt (DMA drains, A-prefetch stays in flight), 1 raw barrier/K-tile.

#define BATCH 4096
#define NGRP  16
#define DIN   512
#define DOUT  512

#define BM 128
#define BN 512
#define BK 64
#define NT (DIN / BK)   // 8 K-tiles

typedef __bf16 bf16x8 __attribute__((ext_vector_type(8)));
typedef float  f32x4  __attribute__((ext_vector_type(4)));
typedef const __attribute__((address_space(1))) void gas_void;
typedef __attribute__((address_space(3))) void las_void;

// ---------- prepass: W fp32 -> bf16 into d_ws ----------
__global__ __launch_bounds__(256)
void wcvt_kernel(const float* __restrict__ W, __bf16* __restrict__ Wb) {
    const int i = (blockIdx.x * 256 + threadIdx.x) * 8;
    f32x4 a = *(const f32x4*)(W + i);
    f32x4 b = *(const f32x4*)(W + i + 4);
    bf16x8 v;
#pragma unroll
    for (int j = 0; j < 4; ++j) { v[j] = (__bf16)a[j]; v[j + 4] = (__bf16)b[j]; }
    *(bf16x8*)(Wb + i) = v;
}

// ---------- main GEMM ----------
__global__ __launch_bounds__(512, 2)
void MultiLinear_48498770706571_kernel(const float* __restrict__ X,
                                       const __bf16* __restrict__ Wb,
                                       const float* __restrict__ Bias,
                                       float* __restrict__ Y) {
    // 512 blocks / 8 XCDs = 64 consecutive tiles (2 full groups) per XCD.
    const int bid = (blockIdx.x & 7) * 64 + (blockIdx.x >> 3);
    const int g   = bid >> 5;          // 32 m-tiles per group, 1 n-tile
    const int mt  = bid & 31;
    const int bm0 = mt * BM;

    __shared__ __bf16 As[2][BM * BK];    // 32 KB: linear 128B rows, chunk-swz
    __shared__ __bf16 BsF[2][BN * BK];   // 128 KB: linear, DMA, chunk-swz

    const int tid  = threadIdx.x;
    const int lane = tid & 63;
    const int w    = tid >> 6;        // 0..7
    const int wn   = w * 64;          // wave n-offset (wm = 0 for all)
    const int l15  = lane & 15;
    const int q    = lane >> 4;       // 0..3

    // A staging: 4 thr/row, 16 floats each; 128 rows by 512 threads.
    const int srow = tid >> 2;        // 0..127
    const int sc2  = (tid & 3) * 2;   // first 16B-chunk (of 8) this thr writes
    const float* pA = X + (size_t)(bm0 + srow) * (NGRP * DIN) + g * DIN + (tid & 3) * 16;

    // B DMA geometry: per wave 64 rows; 8 issues of 1 KB (8 rows x 128 B).
    const int drow_l = lane >> 3;     // 0..7 row within instr
    const int dch    = lane & 7;      // 16B chunk within row
    const __bf16* wbase = Wb + (size_t)g * (DOUT * DIN);

    f32x4 ra[4];   // 16 VGPRs in flight (A only; B is DMA)

#define ISSUE_A(k0)                                                        \
    do {                                                                   \
        const f32x4* qa = (const f32x4*)(pA + (k0));                       \
        ra[0] = qa[0]; ra[1] = qa[1]; ra[2] = qa[2]; ra[3] = qa[3];        \
    } while (0)

    // A write: row srow, logical chunks sc2, sc2+1 -> physical chunk ^ (srow&7)
#define CVT_WRITE_A(buf)                                                   \
    do {                                                                   \
        bf16x8 v0, v1;                                                     \
        _Pragma("unroll")                                                  \
        for (int j = 0; j < 4; ++j) {                                      \
            v0[j] = (__bf16)ra[0][j]; v0[j + 4] = (__bf16)ra[1][j];        \
            v1[j] = (__bf16)ra[2][j]; v1[j + 4] = (__bf16)ra[3][j];        \
        }                                                                  \
        const int s = srow & 7;                                            \
        __bf16* base = &As[buf][srow * BK];                                \
        *(bf16x8*)&base[((sc2 ^ s) << 3)]       = v0;                      \
        *(bf16x8*)&base[(((sc2 + 1) ^ s) << 3)] = v1;                      \
    } while (0)

    // B: LDS linear dest; global source pre-swizzled; reads swizzle back.
#define DMA_B(kt, buf)                                                     \
    do {                                                                   \
        const size_t k0 = (size_t)(kt) * BK;                               \
        _Pragma("unroll")                                                  \
        for (int qq = 0; qq < 8; ++qq) {                                   \
            const int row = (w << 6) + (qq << 3) + drow_l;                 \
            const __bf16* gp = wbase + (size_t)row * DIN + k0              \
                               + ((dch ^ (row & 7)) << 3);                 \
            __builtin_amdgcn_global_load_lds(                              \
                (gas_void*)gp,                                             \
                (las_void*)&BsF[buf][(w << 12) + (qq << 9)], 16, 0, 0);    \
        }                                                                  \
    } while (0)

#define COMPUTE(buf)                                                       \
    do {                                                                   \
        _Pragma("unroll")                                                  \
        for (int kk = 0; kk < 2; ++kk) {                                   \
            bf16x8 af[8], bfr[4];                                          \
            _Pragma("unroll")                                              \
            for (int mi = 0; mi < 8; ++mi) {                               \
                const int row = mi * 16 + l15;                             \
                const int ch  = ((kk << 2) + q) ^ (row & 7);               \
                af[mi] = *(const bf16x8*)&As[buf][row * BK + (ch << 3)];   \
            }                                                              \
            _Pragma("unroll")                                              \
            for (int ni = 0; ni < 4; ++ni) {                               \
                const int brow = wn + ni * 16 + l15;                       \
                const int ch = ((kk << 2) + q) ^ (brow & 7);               \
                bfr[ni] = *(const bf16x8*)&BsF[buf][brow * BK + (ch << 3)]; \
            }                                                              \
            _Pragma("unroll")                                              \
            for (int mi = 0; mi < 8; ++mi)                                 \
                _Pragma("unroll")                                          \
                for (int ni = 0; ni < 4; ++ni)                             \
                    acc[mi][ni] = __builtin_amdgcn_mfma_f32_16x16x32_bf16( \
                        af[mi], bfr[ni], acc[mi][ni], 0, 0, 0);            \
        }                                                                  \
    } while (0)

    f32x4 acc[8][4];
#pragma unroll
    for (int mi = 0; mi < 8; ++mi)
#pragma unroll
        for (int ni = 0; ni < 4; ++ni) acc[mi][ni] = f32x4{0.f, 0.f, 0.f, 0.f};

    // prologue: A(0) regs + DMA B(0) into buf0; write A(0); prefetch A(1).
    ISSUE_A(0);
    DMA_B(0, 0);
    CVT_WRITE_A(0);      // compiler waits ra(0) (vmcnt 8): DMA(0) in flight
    ISSUE_A(BK);         // outstanding: DMA(0)[8] + A(1)[4]

    for (int kt = 0; kt < NT; ++kt) {
        const int cur = kt & 1;
        // Drain DMA(kt): outstanding = DMA(kt)[8 oldest] + ra(kt+1)[4 newer].
        if (kt + 1 < NT)
            asm volatile("s_waitcnt vmcnt(4)" ::: "memory");
        else
            asm volatile("s_waitcnt vmcnt(0)" ::: "memory");  // tail: DMA only
        asm volatile("s_waitcnt lgkmcnt(0)" ::: "memory");
        __builtin_amdgcn_s_barrier();

        // after barrier: all waves done reading buf cur^1 -> WAR-safe refill.
        if (kt + 1 < NT) DMA_B(kt + 1, cur ^ 1);

        COMPUTE(cur);

        if (kt + 1 < NT) {
            CVT_WRITE_A(cur ^ 1);          // drains ra(kt+1), DMA stays in flight
            if (kt + 2 < NT) ISSUE_A((kt + 2) * BK);
        }
    }

    // epilogue: C/D layout col = lane&15, row = (lane>>4)*4 + j (verified R1)
    const int r0 = (lane >> 4) * 4;
    const int c  = lane & 15;
    float bias_n[4];
#pragma unroll
    for (int ni = 0; ni < 4; ++ni)
        bias_n[ni] = Bias[g * DOUT + wn + ni * 16 + c];
#pragma unroll
    for (int mi = 0; mi < 8; ++mi) {
#pragma unroll
        for (int j = 0; j < 4; ++j) {
            const int row = bm0 + mi * 16 + r0 + j;
            float* yrow = Y + (size_t)row * (NGRP * DOUT) + g * DOUT + wn;
#pragma unroll
            for (int ni = 0; ni < 4; ++ni)
                yrow[ni * 16 + c] = acc[mi][ni][j] + bias_n[ni];
        }
    }
#undef ISSUE_A
#undef CVT_WRITE_A
#undef DMA_B
#undef COMPUTE
}

extern "C" void kernel_launch(void* const* d_in, const int* in_sizes, int n_in,
                              void* d_out, int out_size, void* d_ws, size_t ws_size,
                              hipStream_t stream) {
    const float* X    = (const float*)d_in[0];
    const float* W    = (const float*)d_in[1];
    const float* Bias = (const float*)d_in[2];
    float* Y          = (float*)d_out;
    __bf16* Wb        = (__bf16*)d_ws;   // 8 MB scratch

    // prepass: 16*512*512 = 4M elems / (256 thr * 8 elems) = 2048 blocks
    wcvt_kernel<<<2048, 256, 0, stream>>>(W, Wb);

    const int grid = NGRP * (BATCH / BM);  // 16*32 = 512
    MultiLinear_48498770706571_kernel<<<grid, 512, 0, stream>>>(X, Wb, Bias, Y);
}